// Round 1
// baseline (561.429 us; speedup 1.0000x reference)
//
#include <hip/hip_runtime.h>

typedef __attribute__((ext_vector_type(8))) short s16x8;
typedef __attribute__((ext_vector_type(4))) float f32x4;
typedef unsigned short u16;

#define B_SZ 2
#define SEQ 8192
#define KD 1024
#define HD 1024
#define RK 16
#define CH 256
#define NCH 64          // total chunks = B_SZ * SEQ/CH
static constexpr float LR_SC = 0.02f;     // TTT_LR * SCALING
static constexpr float SCALE_OUT = 2.0f;  // SCALING

// ---------- helpers ----------
__device__ __forceinline__ u16 f2b(float f) {
  union { float f; unsigned int u; } c; c.f = f;
  unsigned int u = c.u;
  unsigned int r = (u + 0x7fffu + ((u >> 16) & 1u)) >> 16;
  return (u16)r;
}

__device__ __forceinline__ void async16(const u16* g, u16* l) {
  __builtin_amdgcn_global_load_lds((const __attribute__((address_space(1))) void*)g,
                                   (__attribute__((address_space(3))) void*)l, 16, 0, 0);
}

// ---------- fp32 -> bf16 convert ----------
__global__ __launch_bounds__(256) void cvt_bf16(const float* __restrict__ src,
                                                u16* __restrict__ dst, int n) {
  int i = (blockIdx.x * 256 + threadIdx.x) * 4;
  if (i < n) {
    float4 v = *(const float4*)(src + i);
    ushort4 o; o.x = f2b(v.x); o.y = f2b(v.y); o.z = f2b(v.z); o.w = f2b(v.w);
    *(ushort4*)(dst + i) = o;
  }
}

// ---------- LayerNorm of row s+1 -> shifted bf16; also x -> bf16 ----------
__global__ __launch_bounds__(256) void ln_shift(const float* __restrict__ x,
                                                const float* __restrict__ gamma,
                                                const float* __restrict__ beta,
                                                u16* __restrict__ xb,
                                                u16* __restrict__ shb) {
  int row = blockIdx.x;           // 0..16383
  int t = threadIdx.x;
  int s = row & (SEQ - 1);
  const float* xr = x + (size_t)row * KD;
  // own row -> bf16
  float4 v = *(const float4*)(xr + t * 4);
  ushort4 o; o.x = f2b(v.x); o.y = f2b(v.y); o.z = f2b(v.z); o.w = f2b(v.w);
  *(ushort4*)(xb + (size_t)row * KD + t * 4) = o;

  if (s == SEQ - 1) {  // block-uniform branch
    ushort4 z; z.x = 0; z.y = 0; z.z = 0; z.w = 0;
    *(ushort4*)(shb + (size_t)row * KD + t * 4) = z;
    return;
  }
  const float* xn = xr + KD;      // row+1 (same batch guaranteed)
  float4 w = *(const float4*)(xn + t * 4);
  float s1 = w.x + w.y + w.z + w.w;
  float s2 = w.x * w.x + w.y * w.y + w.z * w.z + w.w * w.w;
  #pragma unroll
  for (int off = 32; off > 0; off >>= 1) {
    s1 += __shfl_down(s1, off);
    s2 += __shfl_down(s2, off);
  }
  __shared__ float red[8];
  int wave = t >> 6, lane = t & 63;
  if (lane == 0) { red[wave * 2] = s1; red[wave * 2 + 1] = s2; }
  __syncthreads();
  float sum = red[0] + red[2] + red[4] + red[6];
  float ssq = red[1] + red[3] + red[5] + red[7];
  float mu = sum * (1.0f / KD);
  float var = ssq * (1.0f / KD) - mu * mu;
  float rstd = rsqrtf(var + 1e-5f);
  float4 g = *(const float4*)(gamma + t * 4);
  float4 bb = *(const float4*)(beta + t * 4);
  ushort4 so;
  so.x = f2b((w.x - mu) * rstd * g.x + bb.x);
  so.y = f2b((w.y - mu) * rstd * g.y + bb.y);
  so.z = f2b((w.z - mu) * rstd * g.z + bb.z);
  so.w = f2b((w.w - mu) * rstd * g.w + bb.w);
  *(ushort4*)(shb + (size_t)row * KD + t * 4) = so;
}

// ---------- bf16 MFMA GEMM: C[M,N] = A[M,K] * B[N,K]^T ----------
__global__ __launch_bounds__(256, 2) void gemm_bt(const u16* __restrict__ A,
                                                  const u16* __restrict__ Bm,
                                                  float* __restrict__ C,
                                                  int M, int N, int Kd) {
  constexpr int BM = 128, BN = 128, BK = 32;
  __shared__ u16 As[BM * BK];
  __shared__ u16 Bs[BN * BK];
  int tid = threadIdx.x;
  int lane = tid & 63, wave = tid >> 6;
  int m0 = blockIdx.y * BM, n0 = blockIdx.x * BN;
  int wm = (wave >> 1) * 64, wn = (wave & 1) * 64;
  int lr = lane & 15, lk = (lane >> 4) * 8;
  f32x4 acc[4][4] = {};

  const u16* gbase; u16* lbase;
  if (wave < 2) { gbase = A + (size_t)(m0 + wave * 64) * Kd; lbase = As + wave * 64 * BK; }
  else          { gbase = Bm + (size_t)(n0 + (wave - 2) * 64) * Kd; lbase = Bs + (wave - 2) * 64 * BK; }
  int srow = lane >> 2, scol = (lane & 3) * 8;
  const u16* gsrc = gbase + (size_t)srow * Kd + scol;

  for (int k0 = 0; k0 < Kd; k0 += BK) {
    #pragma unroll
    for (int i = 0; i < 4; i++)
      async16(gsrc + (size_t)i * 16 * Kd, lbase + i * 16 * BK);
    gsrc += BK;
    __syncthreads();
    s16x8 af[4], bfr[4];
    #pragma unroll
    for (int i = 0; i < 4; i++) af[i] = *(const s16x8*)(As + (wm + i * 16 + lr) * BK + lk);
    #pragma unroll
    for (int j = 0; j < 4; j++) bfr[j] = *(const s16x8*)(Bs + (wn + j * 16 + lr) * BK + lk);
    #pragma unroll
    for (int i = 0; i < 4; i++)
      #pragma unroll
      for (int j = 0; j < 4; j++)
        acc[i][j] = __builtin_amdgcn_mfma_f32_16x16x32_bf16(af[i], bfr[j], acc[i][j], 0, 0, 0);
    __syncthreads();
  }
  int rb = (lane >> 4) * 4, cc = lane & 15;
  #pragma unroll
  for (int i = 0; i < 4; i++)
    #pragma unroll
    for (int j = 0; j < 4; j++)
      #pragma unroll
      for (int p = 0; p < 4; p++)
        C[(size_t)(m0 + wm + i * 16 + rb + p) * N + (n0 + wn + j * 16 + cc)] = acc[i][j][p];
}

// ---------- proj_in = Z @ init_B^T ; proj_err = Vc @ init_A ----------
__global__ __launch_bounds__(64) void proj_kernel(const float* __restrict__ x,
                                                  const float* __restrict__ V,
                                                  const float* __restrict__ initA,
                                                  const float* __restrict__ initB,
                                                  float* __restrict__ proj_in,
                                                  float* __restrict__ proj_err) {
  int g = blockIdx.x;       // row group 0..3
  int chunk = blockIdx.y;   // 0..63
  int which = blockIdx.z;   // 0 -> proj_in, 1 -> proj_err
  int lane = threadIdx.x;
  int c = g * 64 + lane;
  __shared__ float W[16 * 1024];
  const float* src = which ? initA : initB;
  for (int i = lane; i < 4096; i += 64)
    *(float4*)&W[i * 4] = *(const float4*)&src[i * 4];
  __syncthreads();
  float acc[16];
  #pragma unroll
  for (int j = 0; j < 16; j++) acc[j] = 0.f;

  if (which == 0) {
    const float* zr = x + (size_t)(chunk * CH + c) * KD;
    for (int k4 = 0; k4 < 256; k4++) {
      float4 z = *(const float4*)(zr + k4 * 4);
      #pragma unroll
      for (int j = 0; j < 16; j++) {
        float4 wv = *(const float4*)&W[j * 1024 + k4 * 4];   // W = init_B[j][k]
        acc[j] += z.x * wv.x + z.y * wv.y + z.z * wv.z + z.w * wv.w;
      }
    }
    float* o = proj_in + ((size_t)chunk * CH + c) * RK;
    #pragma unroll
    for (int q = 0; q < 4; q++) {
      float4 r; r.x = acc[q*4]; r.y = acc[q*4+1]; r.z = acc[q*4+2]; r.w = acc[q*4+3];
      *(float4*)&o[q * 4] = r;
    }
  } else {
    const float* vr = V + (size_t)(chunk * CH + c) * HD;
    for (int h4 = 0; h4 < 256; h4++) {
      float4 vv = *(const float4*)(vr + h4 * 4);
      #pragma unroll
      for (int u = 0; u < 4; u++) {
        float vs = (u == 0) ? vv.x : (u == 1) ? vv.y : (u == 2) ? vv.z : vv.w;
        int h = h4 * 4 + u;
        const float4* arow = (const float4*)&W[h * 16];      // W = init_A[h][j]
        #pragma unroll
        for (int q = 0; q < 4; q++) {
          float4 a = arow[q];
          acc[q*4+0] += vs * a.x; acc[q*4+1] += vs * a.y;
          acc[q*4+2] += vs * a.z; acc[q*4+3] += vs * a.w;
        }
      }
    }
    float* o = proj_err + ((size_t)chunk * CH + c) * RK;
    #pragma unroll
    for (int q = 0; q < 4; q++) {
      float4 r; r.x = acc[q*4]; r.y = acc[q*4+1]; r.z = acc[q*4+2]; r.w = acc[q*4+3];
      *(float4*)&o[q * 4] = r;
    }
  }
}

// ---------- dA[h][j] = sum_c V[c][h]*proj_in[c][j] ; dB[j][k] = sum_c proj_err[c][j]*Z[c][k] ----------
__global__ __launch_bounds__(256) void dadb_kernel(const float* __restrict__ x,
                                                   const float* __restrict__ V,
                                                   const float* __restrict__ proj_in,
                                                   const float* __restrict__ proj_err,
                                                   float* __restrict__ dA,
                                                   float* __restrict__ dB) {
  int tile = blockIdx.x;    // 0..3
  int chunk = blockIdx.y;
  int which = blockIdx.z;   // 0 -> dA, 1 -> dB
  int t = threadIdx.x;
  __shared__ float P[CH * RK];
  const float* psrc = which ? proj_err : proj_in;
  for (int i = t; i < 1024; i += 256)
    *(float4*)&P[i * 4] = *(const float4*)&psrc[(size_t)chunk * 4096 + i * 4];
  __syncthreads();
  float acc[16];
  #pragma unroll
  for (int j = 0; j < 16; j++) acc[j] = 0.f;
  int col = tile * 256 + t;
  const float* src = which ? (x + (size_t)chunk * CH * KD + col)
                           : (V + (size_t)chunk * CH * HD + col);
  for (int c = 0; c < 256; c++) {
    float v = src[(size_t)c * 1024];
    const float4* pr = (const float4*)&P[c * 16];
    #pragma unroll
    for (int q = 0; q < 4; q++) {
      float4 p = pr[q];
      acc[q*4+0] += v * p.x; acc[q*4+1] += v * p.y;
      acc[q*4+2] += v * p.z; acc[q*4+3] += v * p.w;
    }
  }
  if (which == 0) {
    float* o = dA + (size_t)chunk * 16384 + (size_t)col * 16;
    #pragma unroll
    for (int q = 0; q < 4; q++) {
      float4 r; r.x = acc[q*4]; r.y = acc[q*4+1]; r.z = acc[q*4+2]; r.w = acc[q*4+3];
      *(float4*)&o[q * 4] = r;
    }
  } else {
    float* o = dB + (size_t)chunk * 16384 + col;
    #pragma unroll
    for (int j = 0; j < 16; j++) o[(size_t)j * 1024] = acc[j];
  }
}

// ---------- exclusive cumsum over chunks, scaled by lr ----------
__global__ __launch_bounds__(256) void cumsum_kernel(const float* __restrict__ dA,
                                                     const float* __restrict__ dB,
                                                     float* __restrict__ rawA,
                                                     float* __restrict__ rawB) {
  int idx = blockIdx.x * 256 + threadIdx.x;  // 0..65535
  int which = idx >> 15;
  int rem = idx & 32767;
  int b = rem >> 14;
  int e = rem & 16383;
  const float* src = which ? dB : dA;
  float* dst = which ? rawB : rawA;
  size_t base = (size_t)b * 32 * 16384 + e;
  float run = 0.f;
  for (int i = 0; i < 32; i++) {
    size_t off = base + (size_t)i * 16384;
    float nv = src[off];
    dst[off] = LR_SC * run;
    run += nv;
  }
}

// ---------- joint norm clip coefficient ----------
__global__ __launch_bounds__(256) void coef_kernel(const float* __restrict__ rawA,
                                                   const float* __restrict__ rawB,
                                                   float* __restrict__ coef) {
  int chunk = blockIdx.x, t = threadIdx.x;
  const float* a = rawA + (size_t)chunk * 16384;
  const float* b = rawB + (size_t)chunk * 16384;
  float s = 0.f;
  for (int i = t * 4; i < 16384; i += 1024) {
    float4 v = *(const float4*)(a + i);
    s += v.x*v.x + v.y*v.y + v.z*v.z + v.w*v.w;
    float4 w = *(const float4*)(b + i);
    s += w.x*w.x + w.y*w.y + w.z*w.z + w.w*w.w;
  }
  #pragma unroll
  for (int off = 32; off > 0; off >>= 1) s += __shfl_down(s, off);
  __shared__ float red[4];
  int wave = t >> 6, lane = t & 63;
  if (lane == 0) red[wave] = s;
  __syncthreads();
  if (t == 0) {
    float tot = red[0] + red[1] + red[2] + red[3];
    float n = sqrtf(tot);
    coef[chunk] = fminf(1.0f / (n + 1e-6f), 1.0f);
  }
}

// ---------- A_eff / B_eff ----------
__global__ __launch_bounds__(256) void eff_kernel(const float* __restrict__ initA,
                                                  const float* __restrict__ initB,
                                                  const float* __restrict__ rawA,
                                                  const float* __restrict__ rawB,
                                                  const float* __restrict__ coef,
                                                  float* __restrict__ Aeff,
                                                  float* __restrict__ Beff) {
  int idx = blockIdx.x * 256 + threadIdx.x;   // 0..524287, x4 elements
  int which = idx >> 18;
  int rem = idx & 262143;
  int chunk = rem >> 12;
  int e = (rem & 4095) * 4;
  float cf = coef[chunk];
  const float* ini = which ? initB : initA;
  const float* raw = (which ? rawB : rawA) + (size_t)chunk * 16384;
  float* out = (which ? Beff : Aeff) + (size_t)chunk * 16384;
  float4 iv = *(const float4*)(ini + e);
  float4 rv = *(const float4*)(raw + e);
  float4 r;
  r.x = iv.x - rv.x * cf; r.y = iv.y - rv.y * cf;
  r.z = iv.z - rv.z * cf; r.w = iv.w - rv.w * cf;
  *(float4*)(out + e) = r;
}

// ---------- mid = Z @ B_eff^T ----------
__global__ __launch_bounds__(64) void mid_kernel(const float* __restrict__ x,
                                                 const float* __restrict__ Beff,
                                                 float* __restrict__ mid) {
  int g = blockIdx.x;
  int chunk = blockIdx.y;
  int lane = threadIdx.x;
  int c = g * 64 + lane;
  __shared__ float W[16 * 1024];
  const float* src = Beff + (size_t)chunk * 16384;
  for (int i = lane; i < 4096; i += 64)
    *(float4*)&W[i * 4] = *(const float4*)&src[i * 4];
  __syncthreads();
  float acc[16];
  #pragma unroll
  for (int j = 0; j < 16; j++) acc[j] = 0.f;
  const float* zr = x + (size_t)(chunk * CH + c) * KD;
  for (int k4 = 0; k4 < 256; k4++) {
    float4 z = *(const float4*)(zr + k4 * 4);
    #pragma unroll
    for (int j = 0; j < 16; j++) {
      float4 wv = *(const float4*)&W[j * 1024 + k4 * 4];
      acc[j] += z.x * wv.x + z.y * wv.y + z.z * wv.z + z.w * wv.w;
    }
  }
  float* o = mid + ((size_t)chunk * CH + c) * RK;
  #pragma unroll
  for (int q = 0; q < 4; q++) {
    float4 r; r.x = acc[q*4]; r.y = acc[q*4+1]; r.z = acc[q*4+2]; r.w = acc[q*4+3];
    *(float4*)&o[q * 4] = r;
  }
}

// ---------- out += 2 * mid @ A_eff^T ----------
__global__ __launch_bounds__(256) void lora_kernel(const float* __restrict__ mid,
                                                   const float* __restrict__ Aeff,
                                                   float* __restrict__ out) {
  int tile = blockIdx.x;
  int chunk = blockIdx.y;
  int t = threadIdx.x;
  __shared__ float P[CH * RK];
  const float* msrc = mid + (size_t)chunk * 4096;
  for (int i = t; i < 1024; i += 256)
    *(float4*)&P[i * 4] = *(const float4*)&msrc[i * 4];
  __syncthreads();
  int h = tile * 256 + t;
  const float* ar = Aeff + (size_t)chunk * 16384 + (size_t)h * 16;
  float a[16];
  #pragma unroll
  for (int q = 0; q < 4; q++) {
    float4 v = *(const float4*)(ar + q * 4);
    a[q*4] = v.x; a[q*4+1] = v.y; a[q*4+2] = v.z; a[q*4+3] = v.w;
  }
  float* orow = out + (size_t)chunk * CH * HD + h;
  for (int c = 0; c < 256; c++) {
    const float4* pr = (const float4*)&P[c * 16];
    float s = 0.f;
    #pragma unroll
    for (int q = 0; q < 4; q++) {
      float4 p = pr[q];
      s += p.x * a[q*4] + p.y * a[q*4+1] + p.z * a[q*4+2] + p.w * a[q*4+3];
    }
    orow[(size_t)c * HD] += SCALE_OUT * s;
  }
}

extern "C" void kernel_launch(void* const* d_in, const int* in_sizes, int n_in,
                              void* d_out, int out_size, void* d_ws, size_t ws_size,
                              hipStream_t stream) {
  (void)in_sizes; (void)n_in; (void)out_size; (void)ws_size;
  const float* x     = (const float*)d_in[0];
  const float* Wb    = (const float*)d_in[1];
  const float* initA = (const float*)d_in[2];
  const float* initB = (const float*)d_in[3];
  const float* gamma = (const float*)d_in[4];
  const float* beta  = (const float*)d_in[5];
  const float* Wp    = (const float*)d_in[6];
  float* out = (float*)d_out;

  char* ws = (char*)d_ws;
  size_t off = 0;
  auto alloc = [&](size_t bytes) -> void* {
    void* p = ws + off;
    off = (off + bytes + 255) & ~(size_t)255;
    return p;
  };
  const size_t ROWS = (size_t)B_SZ * SEQ;  // 16384
  u16* xb    = (u16*)alloc(ROWS * KD * 2);
  u16* shb   = (u16*)alloc(ROWS * KD * 2);
  u16* Wbb   = (u16*)alloc((size_t)HD * KD * 2);
  u16* Wpb   = (u16*)alloc((size_t)HD * KD * 2);
  float* V   = (float*)alloc(ROWS * HD * 4);
  float* pin = (float*)alloc((size_t)NCH * CH * RK * 4);
  float* per = (float*)alloc((size_t)NCH * CH * RK * 4);
  float* dA  = (float*)alloc((size_t)NCH * 16384 * 4);
  float* dB  = (float*)alloc((size_t)NCH * 16384 * 4);
  float* rawA= (float*)alloc((size_t)NCH * 16384 * 4);
  float* rawB= (float*)alloc((size_t)NCH * 16384 * 4);
  float* cf  = (float*)alloc(NCH * 4);
  float* Aef = (float*)alloc((size_t)NCH * 16384 * 4);
  float* Bef = (float*)alloc((size_t)NCH * 16384 * 4);
  float* mid = (float*)alloc((size_t)NCH * CH * RK * 4);

  cvt_bf16<<<1024, 256, 0, stream>>>(Wb, Wbb, HD * KD);
  cvt_bf16<<<1024, 256, 0, stream>>>(Wp, Wpb, HD * KD);
  ln_shift<<<ROWS, 256, 0, stream>>>(x, gamma, beta, xb, shb);
  gemm_bt<<<dim3(HD / 128, ROWS / 128), 256, 0, stream>>>(xb, Wbb, out, ROWS, HD, KD);
  gemm_bt<<<dim3(HD / 128, ROWS / 128), 256, 0, stream>>>(shb, Wpb, V, ROWS, HD, KD);
  proj_kernel<<<dim3(4, NCH, 2), 64, 0, stream>>>(x, V, initA, initB, pin, per);
  dadb_kernel<<<dim3(4, NCH, 2), 256, 0, stream>>>(x, V, pin, per, dA, dB);
  cumsum_kernel<<<256, 256, 0, stream>>>(dA, dB, rawA, rawB);
  coef_kernel<<<NCH, 256, 0, stream>>>(rawA, rawB, cf);
  eff_kernel<<<2048, 256, 0, stream>>>(initA, initB, rawA, rawB, cf, Aef, Bef);
  mid_kernel<<<dim3(4, NCH), 64, 0, stream>>>(x, Bef, mid);
  lora_kernel<<<dim3(4, NCH), 256, 0, stream>>>(mid, Aef, out);
}

// Round 2
// 315.806 us; speedup vs baseline: 1.7778x; 1.7778x over previous
//
#include <hip/hip_runtime.h>

typedef __attribute__((ext_vector_type(8))) short s16x8;
typedef __attribute__((ext_vector_type(4))) float f32x4;
typedef unsigned short u16;

#define B_SZ 2
#define SEQ 8192
#define KD 1024
#define HD 1024
#define RK 16
#define CH 256
#define NCH 64          // total chunks = B_SZ * SEQ/CH
static constexpr float LR_SC = 0.02f;     // TTT_LR * SCALING
static constexpr float SCALE_OUT = 2.0f;  // SCALING

// ---------- helpers ----------
__device__ __forceinline__ u16 f2b(float f) {
  union { float f; unsigned int u; } c; c.f = f;
  unsigned int u = c.u;
  unsigned int r = (u + 0x7fffu + ((u >> 16) & 1u)) >> 16;
  return (u16)r;
}
__device__ __forceinline__ float b2f(u16 v) {
  union { unsigned int u; float f; } c; c.u = ((unsigned int)v) << 16; return c.f;
}
__device__ __forceinline__ void async16(const u16* g, u16* l) {
  __builtin_amdgcn_global_load_lds((const __attribute__((address_space(1))) void*)g,
                                   (__attribute__((address_space(3))) void*)l, 16, 0, 0);
}

// ---------- fp32 -> bf16 convert ----------
__global__ __launch_bounds__(256) void cvt_bf16(const float* __restrict__ src,
                                                u16* __restrict__ dst, int n) {
  int i = (blockIdx.x * 256 + threadIdx.x) * 4;
  if (i < n) {
    float4 v = *(const float4*)(src + i);
    ushort4 o; o.x = f2b(v.x); o.y = f2b(v.y); o.z = f2b(v.z); o.w = f2b(v.w);
    *(ushort4*)(dst + i) = o;
  }
}

// ---------- init_A [1024][16] -> bf16 transpose [16][1024] ----------
__global__ __launch_bounds__(256) void cvt_at(const float* __restrict__ A,
                                              u16* __restrict__ At) {
  int i = blockIdx.x * 256 + threadIdx.x;
  if (i < HD * RK) {
    int h = i >> 4, j = i & 15;
    At[(size_t)j * HD + h] = f2b(A[i]);
  }
}

// ---------- x -> bf16; LN of own row -> shb[row-1]; row s==0 zeroes shb[batch_last] ----------
__global__ __launch_bounds__(256) void ln_shift(const float* __restrict__ x,
                                                const float* __restrict__ gamma,
                                                const float* __restrict__ beta,
                                                u16* __restrict__ xb,
                                                u16* __restrict__ shb) {
  int row = blockIdx.x;           // 0..16383
  int t = threadIdx.x;
  int s = row & (SEQ - 1);
  const float* xr = x + (size_t)row * KD;
  float4 v = *(const float4*)(xr + t * 4);
  ushort4 o; o.x = f2b(v.x); o.y = f2b(v.y); o.z = f2b(v.z); o.w = f2b(v.w);
  *(ushort4*)(xb + (size_t)row * KD + t * 4) = o;

  if (s == 0) {  // block-uniform: zero the batch's last shifted row, skip LN
    ushort4 z; z.x = 0; z.y = 0; z.z = 0; z.w = 0;
    *(ushort4*)(shb + ((size_t)row + SEQ - 1) * KD + t * 4) = z;
    return;
  }
  float s1 = v.x + v.y + v.z + v.w;
  float s2 = v.x * v.x + v.y * v.y + v.z * v.z + v.w * v.w;
  #pragma unroll
  for (int off = 32; off > 0; off >>= 1) {
    s1 += __shfl_down(s1, off);
    s2 += __shfl_down(s2, off);
  }
  __shared__ float red[8];
  int wave = t >> 6, lane = t & 63;
  if (lane == 0) { red[wave * 2] = s1; red[wave * 2 + 1] = s2; }
  __syncthreads();
  float sum = red[0] + red[2] + red[4] + red[6];
  float ssq = red[1] + red[3] + red[5] + red[7];
  float mu = sum * (1.0f / KD);
  float var = ssq * (1.0f / KD) - mu * mu;
  float rstd = rsqrtf(var + 1e-5f);
  float4 g = *(const float4*)(gamma + t * 4);
  float4 bb = *(const float4*)(beta + t * 4);
  ushort4 so;
  so.x = f2b((v.x - mu) * rstd * g.x + bb.x);
  so.y = f2b((v.y - mu) * rstd * g.y + bb.y);
  so.z = f2b((v.z - mu) * rstd * g.z + bb.z);
  so.w = f2b((v.w - mu) * rstd * g.w + bb.w);
  *(ushort4*)(shb + (size_t)(row - 1) * KD + t * 4) = so;
}

// ---------- V = shb @ Wp^T, bf16 output ----------
__global__ __launch_bounds__(256, 2) void gemm_v(const u16* __restrict__ A,
                                                 const u16* __restrict__ Bm,
                                                 u16* __restrict__ C) {
  constexpr int BM = 128, BN = 128, BK = 32, N = HD, Kd = KD;
  __shared__ u16 As[BM * BK];
  __shared__ u16 Bs[BN * BK];
  int tid = threadIdx.x;
  int lane = tid & 63, wave = tid >> 6;
  int m0 = blockIdx.y * BM, n0 = blockIdx.x * BN;
  int wm = (wave >> 1) * 64, wn = (wave & 1) * 64;
  int lr = lane & 15, lk = (lane >> 4) * 8;
  f32x4 acc[4][4] = {};

  const u16* gbase; u16* lbase;
  if (wave < 2) { gbase = A + (size_t)(m0 + wave * 64) * Kd; lbase = As + wave * 64 * BK; }
  else          { gbase = Bm + (size_t)(n0 + (wave - 2) * 64) * Kd; lbase = Bs + (wave - 2) * 64 * BK; }
  int srow = lane >> 2, scol = (lane & 3) * 8;
  const u16* gsrc = gbase + (size_t)srow * Kd + scol;

  for (int k0 = 0; k0 < Kd; k0 += BK) {
    #pragma unroll
    for (int i = 0; i < 4; i++)
      async16(gsrc + (size_t)i * 16 * Kd, lbase + i * 16 * BK);
    gsrc += BK;
    __syncthreads();
    s16x8 af[4], bfr[4];
    #pragma unroll
    for (int i = 0; i < 4; i++) af[i] = *(const s16x8*)(As + (wm + i * 16 + lr) * BK + lk);
    #pragma unroll
    for (int j = 0; j < 4; j++) bfr[j] = *(const s16x8*)(Bs + (wn + j * 16 + lr) * BK + lk);
    #pragma unroll
    for (int i = 0; i < 4; i++)
      #pragma unroll
      for (int j = 0; j < 4; j++)
        acc[i][j] = __builtin_amdgcn_mfma_f32_16x16x32_bf16(af[i], bfr[j], acc[i][j], 0, 0, 0);
    __syncthreads();
  }
  int rb = (lane >> 4) * 4, cc = lane & 15;
  #pragma unroll
  for (int i = 0; i < 4; i++)
    #pragma unroll
    for (int j = 0; j < 4; j++)
      #pragma unroll
      for (int p = 0; p < 4; p++)
        C[(size_t)(m0 + wm + i * 16 + rb + p) * N + (n0 + wn + j * 16 + cc)] = f2b(acc[i][j][p]);
}

// ---------- out = xb @ Wb^T + mid2 @ Aeff^T (fp32 output, LoRA K-extension) ----------
__global__ __launch_bounds__(256, 2) void gemm_fused(const u16* __restrict__ A,
                                                     const u16* __restrict__ Bm,
                                                     const u16* __restrict__ mid2,
                                                     const u16* __restrict__ Aef,
                                                     float* __restrict__ C) {
  constexpr int BM = 128, BN = 128, BK = 32, N = HD, Kd = KD;
  __shared__ u16 As[BM * BK];
  __shared__ u16 Bs[BN * BK];
  int tid = threadIdx.x;
  int lane = tid & 63, wave = tid >> 6;
  int m0 = blockIdx.y * BM, n0 = blockIdx.x * BN;
  int wm = (wave >> 1) * 64, wn = (wave & 1) * 64;
  int lr = lane & 15, lk = (lane >> 4) * 8;
  f32x4 acc[4][4] = {};

  const u16* gbase; u16* lbase;
  if (wave < 2) { gbase = A + (size_t)(m0 + wave * 64) * Kd; lbase = As + wave * 64 * BK; }
  else          { gbase = Bm + (size_t)(n0 + (wave - 2) * 64) * Kd; lbase = Bs + (wave - 2) * 64 * BK; }
  int srow = lane >> 2, scol = (lane & 3) * 8;
  const u16* gsrc = gbase + (size_t)srow * Kd + scol;

  for (int k0 = 0; k0 < Kd; k0 += BK) {
    #pragma unroll
    for (int i = 0; i < 4; i++)
      async16(gsrc + (size_t)i * 16 * Kd, lbase + i * 16 * BK);
    gsrc += BK;
    __syncthreads();
    s16x8 af[4], bfr[4];
    #pragma unroll
    for (int i = 0; i < 4; i++) af[i] = *(const s16x8*)(As + (wm + i * 16 + lr) * BK + lk);
    #pragma unroll
    for (int j = 0; j < 4; j++) bfr[j] = *(const s16x8*)(Bs + (wn + j * 16 + lr) * BK + lk);
    #pragma unroll
    for (int i = 0; i < 4; i++)
      #pragma unroll
      for (int j = 0; j < 4; j++)
        acc[i][j] = __builtin_amdgcn_mfma_f32_16x16x32_bf16(af[i], bfr[j], acc[i][j], 0, 0, 0);
    __syncthreads();
  }

  // LoRA K-extension: one zero-padded k-step. chunk is uniform per block (128-row tile in 256-row chunk).
  {
    int chunk = blockIdx.y >> 1;
    const u16* mbase = mid2;
    const u16* abase = Aef + (size_t)chunk * (HD * RK);
    int klane = lane >> 4;        // 0..3; only 0,1 carry real k (j=0..15)
    s16x8 am2[4], bn2[4];
    #pragma unroll
    for (int i = 0; i < 4; i++) {
      if (klane < 2)
        am2[i] = *(const s16x8*)(mbase + (size_t)(m0 + wm + i * 16 + lr) * RK + klane * 8);
      else { s16x8 z = {}; am2[i] = z; }
    }
    #pragma unroll
    for (int j = 0; j < 4; j++) {
      if (klane < 2)
        bn2[j] = *(const s16x8*)(abase + (size_t)(n0 + wn + j * 16 + lr) * RK + klane * 8);
      else { s16x8 z = {}; bn2[j] = z; }
    }
    #pragma unroll
    for (int i = 0; i < 4; i++)
      #pragma unroll
      for (int j = 0; j < 4; j++)
        acc[i][j] = __builtin_amdgcn_mfma_f32_16x16x32_bf16(am2[i], bn2[j], acc[i][j], 0, 0, 0);
  }

  int rb = (lane >> 4) * 4, cc = lane & 15;
  #pragma unroll
  for (int i = 0; i < 4; i++)
    #pragma unroll
    for (int j = 0; j < 4; j++)
      #pragma unroll
      for (int p = 0; p < 4; p++)
        C[(size_t)(m0 + wm + i * 16 + rb + p) * N + (n0 + wn + j * 16 + cc)] = acc[i][j][p];
}

// ---------- rank-16 MFMA: O[M x 16] = X[M x 1024] @ W[16 x 1024]^T ----------
// z=0: proj_in = xb @ initB^T ; z=1: proj_err = Vb @ initA (via transposed initA)
__global__ __launch_bounds__(256) void rank16_proj(const u16* __restrict__ xb,
                                                   const u16* __restrict__ Vb,
                                                   const u16* __restrict__ iBb,
                                                   const u16* __restrict__ iAt,
                                                   float* __restrict__ pin,
                                                   float* __restrict__ per) {
  const u16* X; const u16* W; float* O;
  if (blockIdx.z == 0) { X = xb; W = iBb; O = pin; }
  else                 { X = Vb; W = iAt; O = per; }
  int wave = threadIdx.x >> 6, lane = threadIdx.x & 63;
  int m0 = (blockIdx.x * 4 + wave) * 16;
  int lr = lane & 15, lk = (lane >> 4) * 8;
  const u16* xp = X + (size_t)(m0 + lr) * KD + lk;
  const u16* wp = W + (size_t)lr * KD + lk;
  f32x4 acc = {};
  #pragma unroll 4
  for (int k0 = 0; k0 < KD; k0 += 32) {
    s16x8 a = *(const s16x8*)xp;
    s16x8 b = *(const s16x8*)wp;
    acc = __builtin_amdgcn_mfma_f32_16x16x32_bf16(a, b, acc, 0, 0, 0);
    xp += 32; wp += 32;
  }
  int rb = (lane >> 4) * 4, cc = lane & 15;
  #pragma unroll
  for (int p = 0; p < 4; p++)
    O[(size_t)(m0 + rb + p) * RK + cc] = acc[p];
}

// ---------- mid2 = 2 * (xb @ Beff[chunk]^T), bf16 out ----------
__global__ __launch_bounds__(256) void rank16_mid(const u16* __restrict__ xb,
                                                  const u16* __restrict__ Bef,
                                                  u16* __restrict__ mid2) {
  int wave = threadIdx.x >> 6, lane = threadIdx.x & 63;
  int m0 = (blockIdx.x * 4 + wave) * 16;
  int chunk = m0 >> 8;
  int lr = lane & 15, lk = (lane >> 4) * 8;
  const u16* xp = xb + (size_t)(m0 + lr) * KD + lk;
  const u16* wp = Bef + (size_t)chunk * (RK * KD) + (size_t)lr * KD + lk;
  f32x4 acc = {};
  #pragma unroll 4
  for (int k0 = 0; k0 < KD; k0 += 32) {
    s16x8 a = *(const s16x8*)xp;
    s16x8 b = *(const s16x8*)wp;
    acc = __builtin_amdgcn_mfma_f32_16x16x32_bf16(a, b, acc, 0, 0, 0);
    xp += 32; wp += 32;
  }
  int rb = (lane >> 4) * 4, cc = lane & 15;
  #pragma unroll
  for (int p = 0; p < 4; p++)
    mid2[(size_t)(m0 + rb + p) * RK + cc] = f2b(SCALE_OUT * acc[p]);
}

// ---------- dA[h][j] = sum_c V[c][h]*proj_in[c][j] ; dB[j][k] = sum_c proj_err[c][j]*Z[c][k] ----------
__global__ __launch_bounds__(256) void dadb_kernel(const u16* __restrict__ xb,
                                                   const u16* __restrict__ Vb,
                                                   const float* __restrict__ proj_in,
                                                   const float* __restrict__ proj_err,
                                                   float* __restrict__ dA,
                                                   float* __restrict__ dB) {
  int tile = blockIdx.x;    // 0..3
  int chunk = blockIdx.y;
  int which = blockIdx.z;   // 0 -> dA, 1 -> dB
  int t = threadIdx.x;
  __shared__ float P[CH * RK];
  const float* psrc = which ? proj_err : proj_in;
  for (int i = t; i < 1024; i += 256)
    *(float4*)&P[i * 4] = *(const float4*)&psrc[(size_t)chunk * 4096 + i * 4];
  __syncthreads();
  float acc[16];
  #pragma unroll
  for (int j = 0; j < 16; j++) acc[j] = 0.f;
  int col = tile * 256 + t;
  const u16* src = which ? (xb + (size_t)chunk * CH * KD + col)
                         : (Vb + (size_t)chunk * CH * HD + col);
  for (int c = 0; c < 256; c++) {
    float v = b2f(src[(size_t)c * 1024]);
    const float4* pr = (const float4*)&P[c * 16];
    #pragma unroll
    for (int q = 0; q < 4; q++) {
      float4 p = pr[q];
      acc[q*4+0] += v * p.x; acc[q*4+1] += v * p.y;
      acc[q*4+2] += v * p.z; acc[q*4+3] += v * p.w;
    }
  }
  if (which == 0) {
    float* o = dA + (size_t)chunk * 16384 + (size_t)col * 16;
    #pragma unroll
    for (int q = 0; q < 4; q++) {
      float4 r; r.x = acc[q*4]; r.y = acc[q*4+1]; r.z = acc[q*4+2]; r.w = acc[q*4+3];
      *(float4*)&o[q * 4] = r;
    }
  } else {
    float* o = dB + (size_t)chunk * 16384 + col;
    #pragma unroll
    for (int j = 0; j < 16; j++) o[(size_t)j * 1024] = acc[j];
  }
}

// ---------- exclusive cumsum over chunks, scaled by lr ----------
__global__ __launch_bounds__(256) void cumsum_kernel(const float* __restrict__ dA,
                                                     const float* __restrict__ dB,
                                                     float* __restrict__ rawA,
                                                     float* __restrict__ rawB) {
  int idx = blockIdx.x * 256 + threadIdx.x;  // 0..65535
  int which = idx >> 15;
  int rem = idx & 32767;
  int b = rem >> 14;
  int e = rem & 16383;
  const float* src = which ? dB : dA;
  float* dst = which ? rawB : rawA;
  size_t base = (size_t)b * 32 * 16384 + e;
  float run = 0.f;
  for (int i = 0; i < 32; i++) {
    size_t off = base + (size_t)i * 16384;
    float nv = src[off];
    dst[off] = LR_SC * run;
    run += nv;
  }
}

// ---------- joint norm clip coefficient ----------
__global__ __launch_bounds__(256) void coef_kernel(const float* __restrict__ rawA,
                                                   const float* __restrict__ rawB,
                                                   float* __restrict__ coef) {
  int chunk = blockIdx.x, t = threadIdx.x;
  const float* a = rawA + (size_t)chunk * 16384;
  const float* b = rawB + (size_t)chunk * 16384;
  float s = 0.f;
  for (int i = t * 4; i < 16384; i += 1024) {
    float4 v = *(const float4*)(a + i);
    s += v.x*v.x + v.y*v.y + v.z*v.z + v.w*v.w;
    float4 w = *(const float4*)(b + i);
    s += w.x*w.x + w.y*w.y + w.z*w.z + w.w*w.w;
  }
  #pragma unroll
  for (int off = 32; off > 0; off >>= 1) s += __shfl_down(s, off);
  __shared__ float red[4];
  int wave = t >> 6, lane = t & 63;
  if (lane == 0) red[wave] = s;
  __syncthreads();
  if (t == 0) {
    float tot = red[0] + red[1] + red[2] + red[3];
    float n = sqrtf(tot);
    coef[chunk] = fminf(1.0f / (n + 1e-6f), 1.0f);
  }
}

// ---------- A_eff / B_eff -> bf16 ----------
__global__ __launch_bounds__(256) void eff_kernel(const float* __restrict__ initA,
                                                  const float* __restrict__ initB,
                                                  const float* __restrict__ rawA,
                                                  const float* __restrict__ rawB,
                                                  const float* __restrict__ coef,
                                                  u16* __restrict__ Aef,
                                                  u16* __restrict__ Bef) {
  int idx = blockIdx.x * 256 + threadIdx.x;   // 0..524287, x4 elements
  int which = idx >> 18;
  int rem = idx & 262143;
  int chunk = rem >> 12;
  int e = (rem & 4095) * 4;
  float cf = coef[chunk];
  const float* ini = which ? initB : initA;
  const float* raw = (which ? rawB : rawA) + (size_t)chunk * 16384;
  u16* out = (which ? Bef : Aef) + (size_t)chunk * 16384;
  float4 iv = *(const float4*)(ini + e);
  float4 rv = *(const float4*)(raw + e);
  ushort4 r;
  r.x = f2b(iv.x - rv.x * cf); r.y = f2b(iv.y - rv.y * cf);
  r.z = f2b(iv.z - rv.z * cf); r.w = f2b(iv.w - rv.w * cf);
  *(ushort4*)(out + e) = r;
}

extern "C" void kernel_launch(void* const* d_in, const int* in_sizes, int n_in,
                              void* d_out, int out_size, void* d_ws, size_t ws_size,
                              hipStream_t stream) {
  (void)in_sizes; (void)n_in; (void)out_size; (void)ws_size;
  const float* x     = (const float*)d_in[0];
  const float* Wb    = (const float*)d_in[1];
  const float* initA = (const float*)d_in[2];
  const float* initB = (const float*)d_in[3];
  const float* gamma = (const float*)d_in[4];
  const float* beta  = (const float*)d_in[5];
  const float* Wp    = (const float*)d_in[6];
  float* out = (float*)d_out;

  char* ws = (char*)d_ws;
  size_t off = 0;
  auto alloc = [&](size_t bytes) -> void* {
    void* p = ws + off;
    off = (off + bytes + 255) & ~(size_t)255;
    return p;
  };
  const size_t ROWS = (size_t)B_SZ * SEQ;  // 16384
  u16* xb    = (u16*)alloc(ROWS * KD * 2);
  u16* shb   = (u16*)alloc(ROWS * KD * 2);
  u16* Wbb   = (u16*)alloc((size_t)HD * KD * 2);
  u16* Wpb   = (u16*)alloc((size_t)HD * KD * 2);
  u16* iBb   = (u16*)alloc((size_t)RK * KD * 2);
  u16* iAt   = (u16*)alloc((size_t)RK * HD * 2);
  u16* Vb    = (u16*)alloc(ROWS * HD * 2);
  float* pin = (float*)alloc((size_t)NCH * CH * RK * 4);
  float* per = (float*)alloc((size_t)NCH * CH * RK * 4);
  float* dA  = (float*)alloc((size_t)NCH * 16384 * 4);
  float* dB  = (float*)alloc((size_t)NCH * 16384 * 4);
  float* rawA= (float*)alloc((size_t)NCH * 16384 * 4);
  float* rawB= (float*)alloc((size_t)NCH * 16384 * 4);
  float* cf  = (float*)alloc(NCH * 4);
  u16* Aef   = (u16*)alloc((size_t)NCH * 16384 * 2);
  u16* Bef   = (u16*)alloc((size_t)NCH * 16384 * 2);
  u16* mid2  = (u16*)alloc(ROWS * RK * 2);

  cvt_bf16<<<1024, 256, 0, stream>>>(Wb, Wbb, HD * KD);
  cvt_bf16<<<1024, 256, 0, stream>>>(Wp, Wpb, HD * KD);
  cvt_bf16<<<16, 256, 0, stream>>>(initB, iBb, RK * KD);
  cvt_at<<<64, 256, 0, stream>>>(initA, iAt);
  ln_shift<<<ROWS, 256, 0, stream>>>(x, gamma, beta, xb, shb);
  gemm_v<<<dim3(HD / 128, ROWS / 128), 256, 0, stream>>>(shb, Wpb, Vb);
  rank16_proj<<<dim3(256, 1, 2), 256, 0, stream>>>(xb, Vb, iBb, iAt, pin, per);
  dadb_kernel<<<dim3(4, NCH, 2), 256, 0, stream>>>(xb, Vb, pin, per, dA, dB);
  cumsum_kernel<<<256, 256, 0, stream>>>(dA, dB, rawA, rawB);
  coef_kernel<<<NCH, 256, 0, stream>>>(rawA, rawB, cf);
  eff_kernel<<<2048, 256, 0, stream>>>(initA, initB, rawA, rawB, cf, Aef, Bef);
  rank16_mid<<<256, 256, 0, stream>>>(xb, Bef, mid2);
  gemm_fused<<<dim3(HD / 128, ROWS / 128), 256, 0, stream>>>(xb, Wbb, mid2, Aef, out);
}